// Round 22
// baseline (71.134 us; speedup 1.0000x reference)
//
#include <hip/hip_runtime.h>
#include <hip/hip_bf16.h>
#include <cstdint>

// Problem constants: B=4, T=512, S=512, V=8, M=2, K=4, F=1, Hqk=32, Hv=32, C=256
#define BB 4
#define TT 512
#define SS 512
#define VV 8
#define NROWS (BB * TT * VV)   // 16384

// Head-blocked layout: QKVH[(b*8+v)*16 + slot][512][32], slot = col>>5
//   slots 0..7 = Q (m*4+k), 8..11 = K (V lives in Vt2)
// Vt2[(b*8+v)*4+k][8 chunks][32 h][64 s]  (V transposed, chunk-contiguous)

typedef __attribute__((ext_vector_type(8))) short bf16x8;
typedef __attribute__((ext_vector_type(4))) float f32x4;

static __device__ __forceinline__ short f2bf(float f) {   // cold paths only
  union { float f; unsigned u; } x; x.f = f;
  unsigned r = x.u + 0x7FFFu + ((x.u >> 16) & 1u);  // RNE
  return (short)(r >> 16);
}

// v_cvt_pk_bf16_f32: one instruction, returns (bf16(hi)<<16)|bf16(lo)
static __device__ __forceinline__ unsigned cvt_pk(float lo, float hi) {
  unsigned r;
  asm("v_cvt_pk_bf16_f32 %0, %1, %2" : "=v"(r) : "v"(lo), "v"(hi));
  return r;
}

// async global->LDS, 16B per lane (dest must be linear: base + lane*16)
static __device__ __forceinline__ void gload_lds16(const void* g, void* l) {
  __builtin_amdgcn_global_load_lds(
      (const __attribute__((address_space(1))) void*)g,
      (__attribute__((address_space(3))) void*)l, 16, 0, 0);
}

// ---------------- merged: pack weights (bf16, B^T) + pack mask bits --------
__global__ __launch_bounds__(256) void pack_all_kernel(const float* __restrict__ Wq,
                                                       const float* __restrict__ Wk,
                                                       const float* __restrict__ Wv,
                                                       const float* __restrict__ Wout,
                                                       const int* __restrict__ mask,
                                                       short* __restrict__ WcatT,
                                                       short* __restrict__ WoutT,
                                                       unsigned long long* __restrict__ mask64) {
  if (blockIdx.x < 768) {
    int idx = blockIdx.x * 256 + threadIdx.x;
    const float qscale = 0.17677669529663687f * 1.4426950408889634f; // 1/sqrt(32)*log2e
    if (idx < 512 * 256) {
      int n = idx >> 8, c = idx & 255;
      float val;
      if (n < 256)      val = Wq[c * 256 + n] * qscale;
      else if (n < 384) val = Wk[c * 128 + (n - 256)];
      else              val = Wv[c * 128 + (n - 384)];
      WcatT[idx] = f2bf(val);
    } else {
      int j = idx - 512 * 256;
      int cc = j >> 8, jj = j & 255;
      WoutT[j] = f2bf(Wout[jj * 256 + cc]);
    }
  } else {
    int row = (blockIdx.x - 768) * 4 + (threadIdx.x >> 6);   // one wave per (b,t) row
    int ln = threadIdx.x & 63;
    const int* mrow = mask + (size_t)row * SS;
#pragma unroll
    for (int c = 0; c < 8; ++c) {
      unsigned long long bal = __ballot(mrow[c * 64 + ln] != 0);
      if (ln == 0) mask64[(size_t)row * 8 + c] = bal;
    }
  }
}

// ---------------- bf16 MFMA GEMM: C = A(M x 256) * Bt(N x 256)^T -----------
// 64x128 tile, 256 threads = 4 waves (2x2 of 32x64), 2x4 fragments, BK=64.
// B staged via global_load_lds width-16; A reg-staged with fused cvt (fp32).
// EPI 0: f32 row-major out (N).  EPI 2: bf16 head-blocked scatter; Q/K slots
// -> qkvh planes, V slots (12..15) -> Vt2 transposed (vtrans fused here).
template <int N, bool AF32, int EPI>
__global__ __launch_bounds__(256) void gemm_bf16(const void* __restrict__ Ap,
                                                 const short* __restrict__ Bt,
                                                 void* __restrict__ Cout,
                                                 short* __restrict__ Vt2) {
  __shared__ short As[64][64];
  __shared__ short Bs[128][64];
  const int tid = threadIdx.x;
  const int w = tid >> 6, ln = tid & 63;
  const int wr = (w >> 1) * 32, wc = (w & 1) * 64;
  const int bm = blockIdx.x * 64, bn = blockIdx.y * 128;
  const int lr = ln & 15, lk = (ln >> 4) * 8;
  const int r0 = tid >> 3, ko = (tid & 7) * 8;   // r0 0..31

  f32x4 acc[2][4] = {};

  for (int k0 = 0; k0 < 256; k0 += 64) {
    bf16x8 a[2];
    if constexpr (AF32) {   // issue A reg-loads early (overlap prev compute)
#pragma unroll
      for (int i = 0; i < 2; ++i) {
        size_t row = (size_t)(bm + i * 32 + r0);
        const float* Af = (const float*)Ap;
        float4 f0 = *(const float4*)&Af[row * 256 + k0 + ko];
        float4 f1 = *(const float4*)&Af[row * 256 + k0 + ko + 4];
        uint4 pk = make_uint4(cvt_pk(f0.x, f0.y), cvt_pk(f0.z, f0.w),
                              cvt_pk(f1.x, f1.y), cvt_pk(f1.z, f1.w));
        a[i] = *(bf16x8*)&pk;
      }
    }
    __syncthreads();   // previous iteration's fragment reads done
    // B: async global->LDS, 4 row-chunks of 32
#pragma unroll
    for (int i = 0; i < 4; ++i)
      gload_lds16(&Bt[(size_t)(bn + i * 32 + r0) * 256 + k0 + ko],
                  &Bs[i * 32 + r0][ko]);
    if constexpr (AF32) {
#pragma unroll
      for (int i = 0; i < 2; ++i) *(bf16x8*)&As[i * 32 + r0][ko] = a[i];
    } else {
#pragma unroll
      for (int i = 0; i < 2; ++i)
        gload_lds16(&((const short*)Ap)[(size_t)(bm + i * 32 + r0) * 256 + k0 + ko],
                    &As[i * 32 + r0][ko]);
    }
    __syncthreads();   // drains vmcnt (async loads) + lgkm (ds_writes)

#pragma unroll
    for (int kk = 0; kk < 2; ++kk) {
      bf16x8 af[2], bfr[4];
#pragma unroll
      for (int mi = 0; mi < 2; ++mi)
        af[mi] = *(const bf16x8*)&As[wr + mi * 16 + lr][kk * 32 + lk];
#pragma unroll
      for (int ni = 0; ni < 4; ++ni)
        bfr[ni] = *(const bf16x8*)&Bs[wc + ni * 16 + lr][kk * 32 + lk];
#pragma unroll
      for (int mi = 0; mi < 2; ++mi)
#pragma unroll
        for (int ni = 0; ni < 4; ++ni)
          acc[mi][ni] = __builtin_amdgcn_mfma_f32_16x16x32_bf16(af[mi], bfr[ni], acc[mi][ni], 0, 0, 0);
    }
  }

  const int rowg = (ln >> 4) * 4;
  if constexpr (EPI == 0) {
#pragma unroll
    for (int mi = 0; mi < 2; ++mi)
#pragma unroll
      for (int r = 0; r < 4; ++r) {
        size_t row = bm + wr + mi * 16 + rowg + r;
#pragma unroll
        for (int ni = 0; ni < 4; ++ni)
          ((float*)Cout)[row * N + bn + wc + ni * 16 + lr] = acc[mi][ni][r];
      }
  } else {
    // head-blocked bf16 scatter: col j -> (slot=j>>5, h), slot uniform per ni
    int slotN[4], h16[4];
#pragma unroll
    for (int ni = 0; ni < 4; ++ni) {
      int jb = bn + wc + ni * 16;
      slotN[ni] = jb >> 5;
      h16[ni] = jb & 16;
    }
    short* q16 = (short*)Cout;
#pragma unroll
    for (int mi = 0; mi < 2; ++mi)
#pragma unroll
      for (int r = 0; r < 4; ++r) {
        int row = bm + wr + mi * 16 + rowg + r;
        int t = (row >> 3) & 511;
        int bv = (row >> 12) * 8 + (row & 7);
        unsigned u0 = cvt_pk(acc[mi][0][r], acc[mi][1][r]);
        unsigned u1 = cvt_pk(acc[mi][2][r], acc[mi][3][r]);
        short vals[4] = {(short)u0, (short)(u0 >> 16), (short)u1, (short)(u1 >> 16)};
#pragma unroll
        for (int ni = 0; ni < 4; ++ni) {
          int slot = slotN[ni], h = h16[ni] + lr;
          if (slot < 12) {   // Q/K planes
            q16[((size_t)bv << 18) + slot * 16384 + t * 32 + h] = vals[ni];
          } else {           // V -> Vt2 transposed (fused vtrans)
            Vt2[(((size_t)bv * 4 + (slot - 12)) << 14) + ((t >> 6) << 11) + (h << 6) + (t & 63)] = vals[ni];
          }
        }
      }
  }
}

// ---------------- MFMA flash attention: head-blocked, XCD-swizzled ---------
// 1D grid 1024, bijective XCD swizzle. Per block: t-tile 64, head (b,v,k);
// 4 independent waves. No __syncthreads; LDS only for P round-trip.
// CHANGE vs R20 (phase reorder for in-order issue): per chunk the stream is
// [QK0,exp0,pack0 | QK1,exp1,pack1 | PV0,PV1] — m=1's whole VALU phase hides
// m=0's Pt write->read latency; Pt is chunk-parity double-buffered so c+1's
// writes don't wait on c's reads. Rolled c-loop (full unroll banned).
__global__ __launch_bounds__(256) void attn_mfma(const short* __restrict__ qkvh,
                                                 const short* __restrict__ Vt2,
                                                 const unsigned long long* __restrict__ mask64,
                                                 short* __restrict__ att) {
  const int orig = blockIdx.x;
  const int widx = (orig & 7) * 128 + (orig >> 3);
  const int head = widx >> 3;        // 0..127 = (b*8+v)*4+k
  const int t0 = (widx & 7) * 64;
  const int bv = head >> 2;
  const int b  = bv >> 3;
  const int v  = bv & 7;
  const int k  = head & 3;
  const int tid = threadIdx.x;
  const int w  = tid >> 6;
  const int ln = tid & 63;
  const int gq = ln >> 4;
  const int tr = ln & 15;

  __shared__ __align__(16) short Pt[2][2][4][16][72];   // [par][m][wave][t][s]

  bf16x8 qf[2];  // Q pre-scaled (scale*log2e folded into Wq); slot m*4+k
  {
    const short* qp = qkvh + ((size_t)(bv * 16 + k) * 512 + (t0 + w * 16 + tr)) * 32 + gq * 8;
    qf[0] = *(const bf16x8*)qp;
    qf[1] = *(const bf16x8*)(qp + 4 * 512 * 32);
  }

  f32x4 acc_o[2][2] = {};      // [m][hh], row t=4gq+r, col h=hh*16+tr
  float l_run[2] = {0.f, 0.f};

  const short* kb = qkvh + (size_t)(bv * 16 + 8 + k) * 16384 + gq * 8;   // K head
  const short* vb = Vt2 + (size_t)(bv * 4 + k) * 16384 + tr * 64 + gq * 8;
  const unsigned long long* mrow = mask64 + ((size_t)(b * TT + t0 + w * 16 + tr)) * 8;

  // prologue: chunk 0 fragments + mask
  bf16x8 kf[4], vf[2][2];
  unsigned long long mb;
#pragma unroll
  for (int st = 0; st < 4; ++st)
    kf[st] = *(const bf16x8*)(kb + (size_t)(st * 16 + tr) * 32);
#pragma unroll
  for (int sh = 0; sh < 2; ++sh)
#pragma unroll
    for (int hh = 0; hh < 2; ++hh)
      vf[sh][hh] = *(const bf16x8*)(vb + hh * 16 * 64 + sh * 32);
  mb = mrow[0];

  for (int c = 0; c < 8; ++c) {
    const int par = c & 1;
    bf16x8 kn[4], vn[2][2];
    unsigned long long mbn;
    if (c < 7) {  // issue next chunk's loads; consumed next iteration
#pragma unroll
      for (int st = 0; st < 4; ++st)
        kn[st] = *(const bf16x8*)(kb + (size_t)((c + 1) * 64 + st * 16 + tr) * 32);
#pragma unroll
      for (int sh = 0; sh < 2; ++sh)
#pragma unroll
        for (int hh = 0; hh < 2; ++hh)
          vn[sh][hh] = *(const bf16x8*)(vb + (c + 1) * 2048 + hh * 16 * 64 + sh * 32);
      mbn = mrow[c + 1];
    }

    unsigned mlo = (unsigned)mb, mhi = (unsigned)(mb >> 32);
    bool keep[4][4];
#pragma unroll
    for (int st = 0; st < 4; ++st) {
      unsigned wbits = (st < 2) ? mlo : mhi;
      const int base = (st & 1) * 16 + 4 * gq;
#pragma unroll
      for (int r = 0; r < 4; ++r)
        keep[st][r] = ((wbits >> (base + r)) & 1u) != 0u;
    }

    // ---- phase A (per m): QK^T -> exp2 -> mask -> l -> pack to Pt ----
#pragma unroll
    for (int m = 0; m < 2; ++m) {
      f32x4 lac[4];
#pragma unroll
      for (int st = 0; st < 4; ++st) {
        f32x4 z = {0.f, 0.f, 0.f, 0.f};
        lac[st] = __builtin_amdgcn_mfma_f32_16x16x32_bf16(kf[st], qf[m], z, 0, 0, 0);
      }
      float pl[4][4];
      float rs = 0.f;
#pragma unroll
      for (int st = 0; st < 4; ++st)
#pragma unroll
        for (int r = 0; r < 4; ++r) {
          float e = __builtin_amdgcn_exp2f(lac[st][r]);
          pl[st][r] = keep[st][r] ? e : 0.f;
          rs += pl[st][r];
        }
      rs += __shfl_xor(rs, 16);
      rs += __shfl_xor(rs, 32);
      l_run[m] += rs;
#pragma unroll
      for (int st = 0; st < 4; ++st)
        *(uint2*)&Pt[par][m][w][tr][st * 16 + 4 * gq] =
            make_uint2(cvt_pk(pl[st][0], pl[st][1]), cvt_pk(pl[st][2], pl[st][3]));
    }

    // ---- phase B (per m): PV from Pt (m=0's write latency hidden by m=1 A)
#pragma unroll
    for (int m = 0; m < 2; ++m) {
#pragma unroll
      for (int sh = 0; sh < 2; ++sh) {
        bf16x8 pf = *(const bf16x8*)&Pt[par][m][w][tr][sh * 32 + gq * 8];
#pragma unroll
        for (int hh = 0; hh < 2; ++hh)
          acc_o[m][hh] = __builtin_amdgcn_mfma_f32_16x16x32_bf16(pf, vf[sh][hh], acc_o[m][hh], 0, 0, 0);
      }
    }

    if (c < 7) {
#pragma unroll
      for (int st = 0; st < 4; ++st) kf[st] = kn[st];
#pragma unroll
      for (int sh = 0; sh < 2; ++sh)
#pragma unroll
        for (int hh = 0; hh < 2; ++hh) vf[sh][hh] = vn[sh][hh];
      mb = mbn;
    }
  }

  // epilogue: acc row t=4gq+r; l for that t held by lane 4gq+r
#pragma unroll
  for (int m = 0; m < 2; ++m) {
    float invR[4];
#pragma unroll
    for (int r = 0; r < 4; ++r) invR[r] = 1.f / __shfl(l_run[m], 4 * gq + r);
#pragma unroll
    for (int r = 0; r < 4; ++r) {
      short* dst = att + ((size_t)((b * TT + t0 + w * 16 + 4 * gq + r) * VV + v)) * 256
                 + m * 128 + k * 32 + tr;
      unsigned u = cvt_pk(acc_o[m][0][r] * invR[r], acc_o[m][1][r] * invR[r]);
      dst[0]  = (short)u;
      dst[16] = (short)(u >> 16);
    }
  }
}

extern "C" void kernel_launch(void* const* d_in, const int* in_sizes, int n_in,
                              void* d_out, int out_size, void* d_ws, size_t ws_size,
                              hipStream_t stream) {
  const float* x = (const float*)d_in[0];
  const float* Wq = (const float*)d_in[1];
  const float* Wk = (const float*)d_in[2];
  const float* Wv = (const float*)d_in[3];
  const float* Wout = (const float*)d_in[4];
  const int* mask = (const int*)d_in[5];
  float* out = (float*)d_out;

  // ws layout (bf16 elements unless noted)
  short* WcatT = (short*)d_ws;                    // 512*256
  short* WoutT = WcatT + 512 * 256;               // 256*256
  short* qkvh  = WoutT + 256 * 256;               // 16384*512 head-blocked (16 MB)
  short* att   = qkvh + (size_t)NROWS * 512;      // 16384*256 (8 MB)
  short* Vt2   = att + (size_t)NROWS * 256;       // 128*16384 (4 MB)
  unsigned long long* mask64 = (unsigned long long*)(Vt2 + (size_t)128 * 16384); // 2048*8

  pack_all_kernel<<<768 + 512, 256, 0, stream>>>(Wq, Wk, Wv, Wout, mask, WcatT, WoutT, mask64);
  gemm_bf16<512, true, 2><<<dim3(NROWS / 64, 4), 256, 0, stream>>>(x, WcatT, qkvh, Vt2);
  attn_mfma<<<1024, 256, 0, stream>>>(qkvh, Vt2, mask64, att);
  gemm_bf16<256, false, 0><<<dim3(NROWS / 64, 2), 256, 0, stream>>>(att, WoutT, out, nullptr);
}

// Round 23
// 65.723 us; speedup vs baseline: 1.0823x; 1.0823x over previous
//
#include <hip/hip_runtime.h>
#include <hip/hip_bf16.h>
#include <cstdint>

// Problem constants: B=4, T=512, S=512, V=8, M=2, K=4, F=1, Hqk=32, Hv=32, C=256
#define BB 4
#define TT 512
#define SS 512
#define VV 8
#define NROWS (BB * TT * VV)   // 16384

// Head-blocked layout: QKVH[(b*8+v)*16 + slot][512][32], slot = col>>5
//   slots 0..7 = Q (m*4+k), 8..11 = K (V lives in Vt2)
// Vt2[(b*8+v)*4+k][8 chunks][32 h][64 s]  (V transposed, chunk-contiguous)

typedef __attribute__((ext_vector_type(8))) short bf16x8;
typedef __attribute__((ext_vector_type(4))) float f32x4;

static __device__ __forceinline__ short f2bf(float f) {   // cold paths only
  union { float f; unsigned u; } x; x.f = f;
  unsigned r = x.u + 0x7FFFu + ((x.u >> 16) & 1u);  // RNE
  return (short)(r >> 16);
}

// v_cvt_pk_bf16_f32: one instruction, returns (bf16(hi)<<16)|bf16(lo)
static __device__ __forceinline__ unsigned cvt_pk(float lo, float hi) {
  unsigned r;
  asm("v_cvt_pk_bf16_f32 %0, %1, %2" : "=v"(r) : "v"(lo), "v"(hi));
  return r;
}

// async global->LDS, 16B per lane (dest must be linear: base + lane*16)
static __device__ __forceinline__ void gload_lds16(const void* g, void* l) {
  __builtin_amdgcn_global_load_lds(
      (const __attribute__((address_space(1))) void*)g,
      (__attribute__((address_space(3))) void*)l, 16, 0, 0);
}

// ---------------- merged: pack weights (bf16, B^T) + pack mask bits --------
__global__ __launch_bounds__(256) void pack_all_kernel(const float* __restrict__ Wq,
                                                       const float* __restrict__ Wk,
                                                       const float* __restrict__ Wv,
                                                       const float* __restrict__ Wout,
                                                       const int* __restrict__ mask,
                                                       short* __restrict__ WcatT,
                                                       short* __restrict__ WoutT,
                                                       unsigned long long* __restrict__ mask64) {
  if (blockIdx.x < 768) {
    int idx = blockIdx.x * 256 + threadIdx.x;
    const float qscale = 0.17677669529663687f * 1.4426950408889634f; // 1/sqrt(32)*log2e
    if (idx < 512 * 256) {
      int n = idx >> 8, c = idx & 255;
      float val;
      if (n < 256)      val = Wq[c * 256 + n] * qscale;
      else if (n < 384) val = Wk[c * 128 + (n - 256)];
      else              val = Wv[c * 128 + (n - 384)];
      WcatT[idx] = f2bf(val);
    } else {
      int j = idx - 512 * 256;
      int cc = j >> 8, jj = j & 255;
      WoutT[j] = f2bf(Wout[jj * 256 + cc]);
    }
  } else {
    int row = (blockIdx.x - 768) * 4 + (threadIdx.x >> 6);   // one wave per (b,t) row
    int ln = threadIdx.x & 63;
    const int* mrow = mask + (size_t)row * SS;
#pragma unroll
    for (int c = 0; c < 8; ++c) {
      unsigned long long bal = __ballot(mrow[c * 64 + ln] != 0);
      if (ln == 0) mask64[(size_t)row * 8 + c] = bal;
    }
  }
}

// ---------------- bf16 MFMA GEMM: C = A(M x 256) * Bt(N x 256)^T -----------
// 64x128 tile, 256 threads = 4 waves (2x2 of 32x64), 2x4 fragments, BK=64.
// B staged via global_load_lds width-16; A reg-staged with fused cvt (fp32).
// EPI 0: f32 row-major out (N).  EPI 2: bf16 head-blocked scatter; Q/K slots
// -> qkvh planes, V slots (12..15) -> Vt2 transposed (vtrans fused here).
template <int N, bool AF32, int EPI>
__global__ __launch_bounds__(256) void gemm_bf16(const void* __restrict__ Ap,
                                                 const short* __restrict__ Bt,
                                                 void* __restrict__ Cout,
                                                 short* __restrict__ Vt2) {
  __shared__ short As[64][64];
  __shared__ short Bs[128][64];
  const int tid = threadIdx.x;
  const int w = tid >> 6, ln = tid & 63;
  const int wr = (w >> 1) * 32, wc = (w & 1) * 64;
  const int bm = blockIdx.x * 64, bn = blockIdx.y * 128;
  const int lr = ln & 15, lk = (ln >> 4) * 8;
  const int r0 = tid >> 3, ko = (tid & 7) * 8;   // r0 0..31

  f32x4 acc[2][4] = {};

  for (int k0 = 0; k0 < 256; k0 += 64) {
    bf16x8 a[2];
    if constexpr (AF32) {   // issue A reg-loads early (overlap prev compute)
#pragma unroll
      for (int i = 0; i < 2; ++i) {
        size_t row = (size_t)(bm + i * 32 + r0);
        const float* Af = (const float*)Ap;
        float4 f0 = *(const float4*)&Af[row * 256 + k0 + ko];
        float4 f1 = *(const float4*)&Af[row * 256 + k0 + ko + 4];
        uint4 pk = make_uint4(cvt_pk(f0.x, f0.y), cvt_pk(f0.z, f0.w),
                              cvt_pk(f1.x, f1.y), cvt_pk(f1.z, f1.w));
        a[i] = *(bf16x8*)&pk;
      }
    }
    __syncthreads();   // previous iteration's fragment reads done
    // B: async global->LDS, 4 row-chunks of 32
#pragma unroll
    for (int i = 0; i < 4; ++i)
      gload_lds16(&Bt[(size_t)(bn + i * 32 + r0) * 256 + k0 + ko],
                  &Bs[i * 32 + r0][ko]);
    if constexpr (AF32) {
#pragma unroll
      for (int i = 0; i < 2; ++i) *(bf16x8*)&As[i * 32 + r0][ko] = a[i];
    } else {
#pragma unroll
      for (int i = 0; i < 2; ++i)
        gload_lds16(&((const short*)Ap)[(size_t)(bm + i * 32 + r0) * 256 + k0 + ko],
                    &As[i * 32 + r0][ko]);
    }
    __syncthreads();   // drains vmcnt (async loads) + lgkm (ds_writes)

#pragma unroll
    for (int kk = 0; kk < 2; ++kk) {
      bf16x8 af[2], bfr[4];
#pragma unroll
      for (int mi = 0; mi < 2; ++mi)
        af[mi] = *(const bf16x8*)&As[wr + mi * 16 + lr][kk * 32 + lk];
#pragma unroll
      for (int ni = 0; ni < 4; ++ni)
        bfr[ni] = *(const bf16x8*)&Bs[wc + ni * 16 + lr][kk * 32 + lk];
#pragma unroll
      for (int mi = 0; mi < 2; ++mi)
#pragma unroll
        for (int ni = 0; ni < 4; ++ni)
          acc[mi][ni] = __builtin_amdgcn_mfma_f32_16x16x32_bf16(af[mi], bfr[ni], acc[mi][ni], 0, 0, 0);
    }
  }

  const int rowg = (ln >> 4) * 4;
  if constexpr (EPI == 0) {
#pragma unroll
    for (int mi = 0; mi < 2; ++mi)
#pragma unroll
      for (int r = 0; r < 4; ++r) {
        size_t row = bm + wr + mi * 16 + rowg + r;
#pragma unroll
        for (int ni = 0; ni < 4; ++ni)
          ((float*)Cout)[row * N + bn + wc + ni * 16 + lr] = acc[mi][ni][r];
      }
  } else {
    // head-blocked bf16 scatter: col j -> (slot=j>>5, h), slot uniform per ni
    int slotN[4], h16[4];
#pragma unroll
    for (int ni = 0; ni < 4; ++ni) {
      int jb = bn + wc + ni * 16;
      slotN[ni] = jb >> 5;
      h16[ni] = jb & 16;
    }
    short* q16 = (short*)Cout;
#pragma unroll
    for (int mi = 0; mi < 2; ++mi)
#pragma unroll
      for (int r = 0; r < 4; ++r) {
        int row = bm + wr + mi * 16 + rowg + r;
        int t = (row >> 3) & 511;
        int bv = (row >> 12) * 8 + (row & 7);
        unsigned u0 = cvt_pk(acc[mi][0][r], acc[mi][1][r]);
        unsigned u1 = cvt_pk(acc[mi][2][r], acc[mi][3][r]);
        short vals[4] = {(short)u0, (short)(u0 >> 16), (short)u1, (short)(u1 >> 16)};
#pragma unroll
        for (int ni = 0; ni < 4; ++ni) {
          int slot = slotN[ni], h = h16[ni] + lr;
          if (slot < 12) {   // Q/K planes
            q16[((size_t)bv << 18) + slot * 16384 + t * 32 + h] = vals[ni];
          } else {           // V -> Vt2 transposed (fused vtrans)
            Vt2[(((size_t)bv * 4 + (slot - 12)) << 14) + ((t >> 6) << 11) + (h << 6) + (t & 63)] = vals[ni];
          }
        }
      }
  }
}

// ---------------- MFMA flash attention: head-blocked, XCD-swizzled ---------
// 1D grid 1024, bijective XCD swizzle. Per block: t-tile 64, head (b,v,k);
// 4 independent waves. No __syncthreads; LDS only for P round-trip.
// Best-known configuration (R19): per-m P buffers, interleaved m-chains,
// rolled c-loop (full unroll miscompiles the Pt round-trip; banned),
// builtin exp2, no-max exp2-domain softmax.
__global__ __launch_bounds__(256) void attn_mfma(const short* __restrict__ qkvh,
                                                 const short* __restrict__ Vt2,
                                                 const unsigned long long* __restrict__ mask64,
                                                 short* __restrict__ att) {
  const int orig = blockIdx.x;
  const int widx = (orig & 7) * 128 + (orig >> 3);
  const int head = widx >> 3;        // 0..127 = (b*8+v)*4+k
  const int t0 = (widx & 7) * 64;
  const int bv = head >> 2;
  const int b  = bv >> 3;
  const int v  = bv & 7;
  const int k  = head & 3;
  const int tid = threadIdx.x;
  const int w  = tid >> 6;
  const int ln = tid & 63;
  const int gq = ln >> 4;
  const int tr = ln & 15;

  __shared__ __align__(16) short Pt[2][4][16][72];   // per-m, per-wave P [t][s]

  bf16x8 qf[2];  // Q pre-scaled (scale*log2e folded into Wq); slot m*4+k
  {
    const short* qp = qkvh + ((size_t)(bv * 16 + k) * 512 + (t0 + w * 16 + tr)) * 32 + gq * 8;
    qf[0] = *(const bf16x8*)qp;
    qf[1] = *(const bf16x8*)(qp + 4 * 512 * 32);
  }

  f32x4 acc_o[2][2] = {};      // [m][hh], row t=4gq+r, col h=hh*16+tr
  float l_run[2] = {0.f, 0.f};

  const short* kb = qkvh + (size_t)(bv * 16 + 8 + k) * 16384 + gq * 8;   // K head
  const short* vb = Vt2 + (size_t)(bv * 4 + k) * 16384 + tr * 64 + gq * 8;
  const unsigned long long* mrow = mask64 + ((size_t)(b * TT + t0 + w * 16 + tr)) * 8;

  // prologue: chunk 0 fragments + mask
  bf16x8 kf[4], vf[2][2];
  unsigned long long mb;
#pragma unroll
  for (int st = 0; st < 4; ++st)
    kf[st] = *(const bf16x8*)(kb + (size_t)(st * 16 + tr) * 32);
#pragma unroll
  for (int sh = 0; sh < 2; ++sh)
#pragma unroll
    for (int hh = 0; hh < 2; ++hh)
      vf[sh][hh] = *(const bf16x8*)(vb + hh * 16 * 64 + sh * 32);
  mb = mrow[0];

  for (int c = 0; c < 8; ++c) {
    bf16x8 kn[4], vn[2][2];
    unsigned long long mbn;
    if (c < 7) {  // issue next chunk's loads; consumed next iteration
#pragma unroll
      for (int st = 0; st < 4; ++st)
        kn[st] = *(const bf16x8*)(kb + (size_t)((c + 1) * 64 + st * 16 + tr) * 32);
#pragma unroll
      for (int sh = 0; sh < 2; ++sh)
#pragma unroll
        for (int hh = 0; hh < 2; ++hh)
          vn[sh][hh] = *(const bf16x8*)(vb + (c + 1) * 2048 + hh * 16 * 64 + sh * 32);
      mbn = mrow[c + 1];
    }

    unsigned mlo = (unsigned)mb, mhi = (unsigned)(mb >> 32);
    float bias[4][4];
#pragma unroll
    for (int st = 0; st < 4; ++st) {
      unsigned wbits = (st < 2) ? mlo : mhi;
      const int base = (st & 1) * 16 + 4 * gq;
#pragma unroll
      for (int r = 0; r < 4; ++r)
        bias[st][r] = ((wbits >> (base + r)) & 1u) ? 0.f : -INFINITY;
    }

#pragma unroll
    for (int m = 0; m < 2; ++m) {
      // swapped QK^T: D[s][t], col t=tr, row s=st*16+4gq+r (log2 domain)
      f32x4 lac[4];
#pragma unroll
      for (int st = 0; st < 4; ++st) {
        f32x4 z = {0.f, 0.f, 0.f, 0.f};
        lac[st] = __builtin_amdgcn_mfma_f32_16x16x32_bf16(kf[st], qf[m], z, 0, 0, 0);
      }
      // no-max softmax: p = exp2(logit + bias), raw v_exp_f32
      float pl[4][4];
      float rs = 0.f;
#pragma unroll
      for (int st = 0; st < 4; ++st)
#pragma unroll
        for (int r = 0; r < 4; ++r) {
          pl[st][r] = __builtin_amdgcn_exp2f(lac[st][r] + bias[st][r]);  // exp2(-inf)=0
          rs += pl[st][r];
        }
      rs += __shfl_xor(rs, 16);
      rs += __shfl_xor(rs, 32);
      l_run[m] += rs;

      // P pack -> per-m per-wave LDS (layout transpose), then PV
#pragma unroll
      for (int st = 0; st < 4; ++st)
        *(uint2*)&Pt[m][w][tr][st * 16 + 4 * gq] =
            make_uint2(cvt_pk(pl[st][0], pl[st][1]), cvt_pk(pl[st][2], pl[st][3]));
#pragma unroll
      for (int sh = 0; sh < 2; ++sh) {
        bf16x8 pf = *(const bf16x8*)&Pt[m][w][tr][sh * 32 + gq * 8];
#pragma unroll
        for (int hh = 0; hh < 2; ++hh)
          acc_o[m][hh] = __builtin_amdgcn_mfma_f32_16x16x32_bf16(pf, vf[sh][hh], acc_o[m][hh], 0, 0, 0);
      }
    }

    if (c < 7) {
#pragma unroll
      for (int st = 0; st < 4; ++st) kf[st] = kn[st];
#pragma unroll
      for (int sh = 0; sh < 2; ++sh)
#pragma unroll
        for (int hh = 0; hh < 2; ++hh) vf[sh][hh] = vn[sh][hh];
      mb = mbn;
    }
  }

  // epilogue: acc row t=4gq+r; l for that t held by lane 4gq+r
#pragma unroll
  for (int m = 0; m < 2; ++m) {
    float invR[4];
#pragma unroll
    for (int r = 0; r < 4; ++r) invR[r] = 1.f / __shfl(l_run[m], 4 * gq + r);
#pragma unroll
    for (int r = 0; r < 4; ++r) {
      short* dst = att + ((size_t)((b * TT + t0 + w * 16 + 4 * gq + r) * VV + v)) * 256
                 + m * 128 + k * 32 + tr;
      unsigned u = cvt_pk(acc_o[m][0][r] * invR[r], acc_o[m][1][r] * invR[r]);
      dst[0]  = (short)u;
      dst[16] = (short)(u >> 16);
    }
  }
}

extern "C" void kernel_launch(void* const* d_in, const int* in_sizes, int n_in,
                              void* d_out, int out_size, void* d_ws, size_t ws_size,
                              hipStream_t stream) {
  const float* x = (const float*)d_in[0];
  const float* Wq = (const float*)d_in[1];
  const float* Wk = (const float*)d_in[2];
  const float* Wv = (const float*)d_in[3];
  const float* Wout = (const float*)d_in[4];
  const int* mask = (const int*)d_in[5];
  float* out = (float*)d_out;

  // ws layout (bf16 elements unless noted)
  short* WcatT = (short*)d_ws;                    // 512*256
  short* WoutT = WcatT + 512 * 256;               // 256*256
  short* qkvh  = WoutT + 256 * 256;               // 16384*512 head-blocked (16 MB)
  short* att   = qkvh + (size_t)NROWS * 512;      // 16384*256 (8 MB)
  short* Vt2   = att + (size_t)NROWS * 256;       // 128*16384 (4 MB)
  unsigned long long* mask64 = (unsigned long long*)(Vt2 + (size_t)128 * 16384); // 2048*8

  pack_all_kernel<<<768 + 512, 256, 0, stream>>>(Wq, Wk, Wv, Wout, mask, WcatT, WoutT, mask64);
  gemm_bf16<512, true, 2><<<dim3(NROWS / 64, 4), 256, 0, stream>>>(x, WcatT, qkvh, Vt2);
  attn_mfma<<<1024, 256, 0, stream>>>(qkvh, Vt2, mask64, att);
  gemm_bf16<256, false, 0><<<dim3(NROWS / 64, 2), 256, 0, stream>>>(att, WoutT, out, nullptr);
}